// Round 7
// baseline (14.388 us; speedup 1.0000x reference)
//
#include <hip/hip_runtime.h>
#include <math.h>

#define IMG_OUT 64
#define WIN 12          // per-lane band window (fine channels)
#define PSTRIDE 13      // prefix row stride (words); gcd(13,32)=1 -> conflict-free

__global__ __launch_bounds__(128, 8) void cube_sim_kernel(
    const float* __restrict__ freqs,
    const float* __restrict__ p_incl,
    const float* __restrict__ p_rot,
    const float* __restrict__ p_lb,
    const float* __restrict__ p_vshift,
    const float* __restrict__ p_vmax,
    const float* __restrict__ p_rturn,
    const float* __restrict__ p_i0,
    const float* __restrict__ p_rd,
    const float* __restrict__ p_hz,
    float* __restrict__ out)
{
    const int t    = threadIdx.x;        // 0..127
    const int w    = t >> 6;             // wave 0/1
    const int lane = t & 63;
    const int p    = lane >> 4;          // internal pixel 0..3
    const int zseg = (w << 4) | (lane & 15);   // 0..31, 4 z-points each
    const int xo = blockIdx.x, yo = blockIdx.y;

    __shared__ float s_P[128 * PSTRIDE];   // per-row prefix sums (13 entries)
    __shared__ int   s_base[128];
    __shared__ float s_part[2][16];

    // ---- scalars ----
    const float incl   = p_incl[0];
    const float rot    = p_rot[0];
    const float lb     = p_lb[0];
    const float vshift = p_vshift[0];
    const float vmx    = p_vmax[0];
    const float rturn  = p_rturn[0];
    const float i0     = p_i0[0];
    const float rd     = p_rd[0];
    const float hz     = p_hz[0];

    const float LOG2E = 1.4426950408889634f;
    const float ci = __cosf(incl), si = __sinf(incl);
    const float cr = __cosf(rot),  sr = __sinf(rot);

    const float K1   = 299792.458f / 230.538f;      // C_KMS / F_REST
    const float f_lo = freqs[0];
    const float df   = (freqs[15] - f_lo) * (1.0f / 63.0f);
    const float beta = K1 * df;                     // km/s per fine channel
    const float alpha = 299792.458f - K1 * (f_lo - 2.0f * df) - vshift;
    const float inv_beta = __builtin_amdgcn_rcpf(beta);

    const float rlb = __builtin_amdgcn_rcpf(lb);
    const float sgs = 1.20112240878645f * rlb;      // sqrt(log2 e)/lb
    const float bp  = beta * sgs;                   // channel pitch, d' units

    const float step  = 2000.0f / 127.0f;
    const float invrt = __builtin_amdgcn_rcpf(rturn);
    const float cA_r  = -LOG2E * __builtin_amdgcn_rcpf(rd);
    const float cA_z  = -LOG2E * __builtin_amdgcn_rcpf(hz);

    // ---- geometry: this lane's pixel, 4 z-points ----
    const float x = -1000.0f + (float)(2 * xo + (p >> 1)) * step;
    const float y = -1000.0f + (float)(2 * yo + (p & 1)) * step;
    const float rx   = cr * x - sr * y;
    const float u0   = sr * x + cr * y;
    const float crx  = -si * vmx * 0.636619772367581f * rx;  // v = crx*atan(t)/rad
    const float rx2e = fmaf(rx, rx, 1e-12f);
    const float z0   = -1000.0f + (float)(zseg * 4) * step;

    float v[4], A[4];
    #pragma unroll
    for (int k = 0; k < 4; ++k) {
        const float z  = z0 + (float)k * step;
        const float ry = ci * u0 - si * z;
        const float rz = si * u0 + ci * z;
        const float r2 = fmaf(ry, ry, rx2e);
        const float ir = __builtin_amdgcn_rsqf(r2);
        const float rad = r2 * ir;
        // cheap atan: tm = min(t, 1/t); 5-coef poly (err ~1e-5 rad); reflect
        const float tg = rad * invrt;
        const float tm = fminf(tg, __builtin_amdgcn_rcpf(tg));
        const float x2 = tm * tm;
        float pl = fmaf(x2, 0.0208351f, -0.0851330f);
        pl = fmaf(x2, pl, 0.1801410f);
        pl = fmaf(x2, pl, -0.3302995f);
        pl = fmaf(x2, pl, 0.9998660f);
        pl *= tm;
        const float at = (tg > 1.0f) ? (1.57079632679f - pl) : pl;
        v[k] = crx * at * ir;                               // v_los
        A[k] = fmaf(rad, cA_r, fabsf(rz) * cA_z);           // log2 intensity
    }

    // ---- per-lane band base ----
    float vlo = fminf(fminf(v[0], v[1]), fminf(v[2], v[3]));
    float vhi = fmaxf(fmaxf(v[0], v[1]), fmaxf(v[2], v[3]));
    const float mid = 0.5f * (vlo + vhi);
    int basei = (int)floorf((alpha - mid) * inv_beta) - 5;
    basei = min(max(basei, 0), 64 - WIN);
    const float Wb = fmaf(-beta, (float)basei, alpha);

    // ---- 4z x 12ch KDE, register-resident ----
    float acc[WIN];
    #pragma unroll
    for (int j = 0; j < WIN; ++j) acc[j] = 0.0f;

    #pragma unroll
    for (int k = 0; k < 4; ++k) {
        const float Wk = sgs * (Wb - v[k]);
        const float Ak = A[k];
        #pragma unroll
        for (int j = 0; j < WIN; ++j) {
            const float d = fmaf(-bp, (float)j, Wk);
            acc[j] += __builtin_amdgcn_exp2f(fmaf(-d, d, Ak));
        }
    }

    // ---- publish prefix sums: P[0]=0, P[j+1]=P[j]+acc[j] ----
    const int rowb = t * PSTRIDE;
    float P = 0.0f;
    s_P[rowb] = 0.0f;
    #pragma unroll
    for (int j = 0; j < WIN; ++j) { P += acc[j]; s_P[rowb + j + 1] = P; }
    s_base[t] = basei;
    __syncthreads();

    // ---- gather: 8 lanes per coarse channel, 16 rows each, P[hi]-P[lo] ----
    const int c  = t & 15;               // coarse channel
    const int g  = t >> 4;               // row group 0..7
    const int c4 = c * 4;
    float s = 0.0f;
    #pragma unroll
    for (int i = 0; i < 16; ++i) {
        const int r = g * 16 + i;
        const int b = s_base[r];         // group-uniform -> broadcast
        int lo = c4 - b;
        int hi = lo + 4;
        lo = min(max(lo, 0), WIN);
        hi = min(max(hi, 0), WIN);
        s += s_P[r * PSTRIDE + hi] - s_P[r * PSTRIDE + lo];
    }
    s += __shfl_xor(s, 16);
    s += __shfl_xor(s, 32);
    if (lane < 16) s_part[w][lane] = s;
    __syncthreads();

    // ---- combine waves, scale, write ----
    if (t < 16) {
        const float sum = s_part[0][t] + s_part[1][t];
        // 1/16 pool * i0 / sqrt(2*pi*lb^2)
        const float scale = i0 * 0.0625f * 0.3989422804014327f * rlb;
        out[t * (IMG_OUT * IMG_OUT) + xo * IMG_OUT + yo] = sum * scale;
    }
}

extern "C" void kernel_launch(void* const* d_in, const int* in_sizes, int n_in,
                              void* d_out, int out_size, void* d_ws, size_t ws_size,
                              hipStream_t stream) {
    (void)in_sizes; (void)n_in; (void)d_ws; (void)ws_size; (void)out_size;
    const float* freqs  = (const float*)d_in[0];
    const float* incl   = (const float*)d_in[1];
    const float* rot    = (const float*)d_in[2];
    const float* lb     = (const float*)d_in[3];
    const float* vshift = (const float*)d_in[4];
    const float* vmax   = (const float*)d_in[5];
    const float* rturn  = (const float*)d_in[6];
    const float* i0     = (const float*)d_in[7];
    const float* rd     = (const float*)d_in[8];
    const float* hz     = (const float*)d_in[9];
    float* out = (float*)d_out;

    dim3 grid(IMG_OUT, IMG_OUT);
    dim3 block(128);
    hipLaunchKernelGGL(cube_sim_kernel, grid, block, 0, stream,
                       freqs, incl, rot, lb, vshift, vmax, rturn, i0, rd, hz, out);
}

// Round 9
// 12.661 us; speedup vs baseline: 1.1364x; 1.1364x over previous
//
#include <hip/hip_runtime.h>
#include <math.h>

#define IMG_OUT 64
#define WIN 14          // per-lane band window (fine channels)
#define PSTRIDE 17      // LDS row stride (words); rows 32 apart alias 2-way = free

__global__ __launch_bounds__(64) void cube_sim_kernel(
    const float* __restrict__ freqs,
    const float* __restrict__ p_incl,
    const float* __restrict__ p_rot,
    const float* __restrict__ p_lb,
    const float* __restrict__ p_vshift,
    const float* __restrict__ p_vmax,
    const float* __restrict__ p_rturn,
    const float* __restrict__ p_i0,
    const float* __restrict__ p_rd,
    const float* __restrict__ p_hz,
    float* __restrict__ out)
{
    const int lane = threadIdx.x;      // 0..63
    const int xo = blockIdx.x, yo = blockIdx.y;
    const int p  = lane >> 4;          // internal pixel 0..3
    const int zb = lane & 15;          // z-block (8 z each)

    __shared__ float s_P[64 * PSTRIDE + 4];   // per-row prefix sums (15 entries)

    // ---- scalars ----
    const float incl   = p_incl[0];
    const float rot    = p_rot[0];
    const float lb     = p_lb[0];
    const float vshift = p_vshift[0];
    const float vmx    = p_vmax[0];
    const float rturn  = p_rturn[0];
    const float i0     = p_i0[0];
    const float rd     = p_rd[0];
    const float hz     = p_hz[0];

    const float LOG2E = 1.4426950408889634f;
    const float ci = __cosf(incl), si = __sinf(incl);
    const float cr = __cosf(rot),  sr = __sinf(rot);

    const float K1   = 299792.458f / 230.538f;      // C_KMS / F_REST
    const float f_lo = freqs[0];
    const float df   = (freqs[15] - f_lo) * (1.0f / 63.0f);
    const float beta = K1 * df;                     // km/s per fine channel
    const float alpha = 299792.458f - K1 * (f_lo - 2.0f * df) - vshift;
    const float inv_beta = __builtin_amdgcn_rcpf(beta);

    const float rlb = __builtin_amdgcn_rcpf(lb);
    const float sgs = 1.20112240878645f * rlb;      // sqrt(log2 e)/lb
    const float bp  = beta * sgs;                   // channel pitch, d' units
    const float tbp = 2.0f * bp;
    const float nbpsq = -bp * bp;

    // wave-uniform Gaussian-lattice constants c_j = 2^(-bp^2 j^2)
    float cj[WIN];
    #pragma unroll
    for (int j = 0; j < WIN; ++j)
        cj[j] = __builtin_amdgcn_exp2f(nbpsq * (float)(j * j));

    const float step  = 2000.0f / 127.0f;
    const float invrt = __builtin_amdgcn_rcpf(rturn);
    const float cA_r  = -LOG2E * __builtin_amdgcn_rcpf(rd);
    const float cA_z  = -LOG2E * __builtin_amdgcn_rcpf(hz);

    // ---- geometry: this lane's pixel, 8 z-points ----
    const float x = -1000.0f + (float)(2 * xo + (p >> 1)) * step;
    const float y = -1000.0f + (float)(2 * yo + (p & 1)) * step;
    const float rx   = cr * x - sr * y;
    const float u0   = sr * x + cr * y;
    const float crx  = -si * vmx * 0.636619772367581f * rx;  // v = crx*atan(t)/rad
    const float rx2e = fmaf(rx, rx, 1e-12f);
    const float zb0  = -1000.0f + (float)(zb * 8) * step;

    float v[8], A[8];
    #pragma unroll
    for (int k = 0; k < 8; ++k) {
        const float z  = zb0 + (float)k * step;
        const float ry = ci * u0 - si * z;
        const float rz = si * u0 + ci * z;
        const float r2 = fmaf(ry, ry, rx2e);
        const float ir = __builtin_amdgcn_rsqf(r2);
        const float rad = r2 * ir;
        // cheap atan: tm = min(t, 1/t); 5-coef poly (err ~1e-5 rad); reflect
        const float tg = rad * invrt;
        const float tm = fminf(tg, __builtin_amdgcn_rcpf(tg));
        const float x2 = tm * tm;
        float pl = fmaf(x2, 0.0208351f, -0.0851330f);
        pl = fmaf(x2, pl, 0.1801410f);
        pl = fmaf(x2, pl, -0.3302995f);
        pl = fmaf(x2, pl, 0.9998660f);
        pl *= tm;
        const float at = (tg > 1.0f) ? (1.57079632679f - pl) : pl;
        v[k] = crx * at * ir;                               // v_los
        A[k] = fmaf(rad, cA_r, fabsf(rz) * cA_z);           // log2 intensity
    }

    // ---- per-lane band base (floor-centering -> symmetric +-6.5ch coverage) ----
    float vlo = v[0], vhi = v[0];
    #pragma unroll
    for (int k = 1; k < 8; ++k) { vlo = fminf(vlo, v[k]); vhi = fmaxf(vhi, v[k]); }
    const float mid = 0.5f * (vlo + vhi);
    int basei = (int)floorf((alpha - mid) * inv_beta) - 6;
    basei = min(max(basei, 0), 64 - WIN);
    const float Wb = fmaf(-beta, (float)basei, alpha);

    // ---- 8z x 14ch KDE, factorized: term_j = E * rho^j * c_j  (2 exp2/z) ----
    float acc[WIN];
    #pragma unroll
    for (int j = 0; j < WIN; ++j) acc[j] = 0.0f;

    #pragma unroll
    for (int k = 0; k < 8; ++k) {
        const float Wk  = sgs * (Wb - v[k]);
        const float E   = __builtin_amdgcn_exp2f(fmaf(-Wk, Wk, A[k])); // 2^(A-W^2)
        const float rho = __builtin_amdgcn_exp2f(tbp * Wk);            // 2^(2bp*W)
        const float rho2 = rho * rho;
        const float rho4 = rho2 * rho2;
        float tj[WIN];
        tj[0] = E;
        tj[1] = E * rho;
        tj[2] = E * rho2;
        tj[3] = tj[1] * rho2;
        #pragma unroll
        for (int j = 4; j < WIN; ++j) tj[j] = tj[j - 4] * rho4;
        #pragma unroll
        for (int j = 0; j < WIN; ++j) acc[j] = fmaf(tj[j], cj[j], acc[j]);
    }

    // ---- publish prefix sums: P[0]=0, P[j+1]=P[j]+acc[j] ----
    const int rowb = lane * PSTRIDE;
    float P = 0.0f;
    s_P[rowb] = 0.0f;
    #pragma unroll
    for (int j = 0; j < WIN; ++j) { P += acc[j]; s_P[rowb + j + 1] = P; }
    __syncthreads();

    // ---- gather: 4 lanes per coarse channel, 16 rows each, via P[hi]-P[lo] ----
    const int t16 = lane & 15;           // coarse channel
    const int g   = lane >> 4;           // row group
    const int c4  = t16 * 4;             // first fine channel of coarse t16
    float s = 0.0f;
    #pragma unroll
    for (int i = 0; i < 16; ++i) {
        const int r = g * 16 + i;
        const int b = __shfl(basei, r);
        int lo = c4 - b;
        int hi = lo + 4;
        lo = min(max(lo, 0), WIN);
        hi = min(max(hi, 0), WIN);
        s += s_P[r * PSTRIDE + hi] - s_P[r * PSTRIDE + lo];
    }
    s += __shfl_xor(s, 16);
    s += __shfl_xor(s, 32);

    if (lane < 16) {
        // 1/16 pool * i0 / sqrt(2*pi*lb^2)
        const float scale = i0 * 0.0625f * 0.3989422804014327f * rlb;
        out[t16 * (IMG_OUT * IMG_OUT) + xo * IMG_OUT + yo] = s * scale;
    }
}

extern "C" void kernel_launch(void* const* d_in, const int* in_sizes, int n_in,
                              void* d_out, int out_size, void* d_ws, size_t ws_size,
                              hipStream_t stream) {
    (void)in_sizes; (void)n_in; (void)d_ws; (void)ws_size; (void)out_size;
    const float* freqs  = (const float*)d_in[0];
    const float* incl   = (const float*)d_in[1];
    const float* rot    = (const float*)d_in[2];
    const float* lb     = (const float*)d_in[3];
    const float* vshift = (const float*)d_in[4];
    const float* vmax   = (const float*)d_in[5];
    const float* rturn  = (const float*)d_in[6];
    const float* i0     = (const float*)d_in[7];
    const float* rd     = (const float*)d_in[8];
    const float* hz     = (const float*)d_in[9];
    float* out = (float*)d_out;

    dim3 grid(IMG_OUT, IMG_OUT);
    dim3 block(64);
    hipLaunchKernelGGL(cube_sim_kernel, grid, block, 0, stream,
                       freqs, incl, rot, lb, vshift, vmax, rturn, i0, rd, hz, out);
}

// Round 10
// 11.540 us; speedup vs baseline: 1.2468x; 1.0971x over previous
//
#include <hip/hip_runtime.h>
#include <math.h>

#define IMG_OUT 64
#define WIN 12          // per-lane band window (fine channels) — proven in round 7
#define PSTRIDE 13      // prefix row stride (words); gcd(13,32)=1 -> 2-way alias = free

__global__ __launch_bounds__(64, 4) void cube_sim_kernel(
    const float* __restrict__ freqs,
    const float* __restrict__ p_incl,
    const float* __restrict__ p_rot,
    const float* __restrict__ p_lb,
    const float* __restrict__ p_vshift,
    const float* __restrict__ p_vmax,
    const float* __restrict__ p_rturn,
    const float* __restrict__ p_i0,
    const float* __restrict__ p_rd,
    const float* __restrict__ p_hz,
    float* __restrict__ out)
{
    const int lane = threadIdx.x;      // 0..63
    const int xo = blockIdx.x, yo = blockIdx.y;
    const int p  = lane >> 4;          // internal pixel 0..3
    const int zb = lane & 15;          // z-block (8 z each)

    __shared__ float s_P[64 * PSTRIDE];   // per-row prefix sums (13 entries)
    __shared__ int   s_base[64];          // per-row band base

    // ---- scalars (uniform -> s_load) ----
    const float incl   = p_incl[0];
    const float rot    = p_rot[0];
    const float lb     = p_lb[0];
    const float vshift = p_vshift[0];
    const float vmx    = p_vmax[0];
    const float rturn  = p_rturn[0];
    const float i0     = p_i0[0];
    const float rd     = p_rd[0];
    const float hz     = p_hz[0];

    const float LOG2E = 1.4426950408889634f;
    const float ci = __cosf(incl), si = __sinf(incl);
    const float cr = __cosf(rot),  sr = __sinf(rot);

    const float K1   = 299792.458f / 230.538f;      // C_KMS / F_REST
    const float f_lo = freqs[0];
    const float df   = (freqs[15] - f_lo) * (1.0f / 63.0f);
    const float beta = K1 * df;                     // km/s per fine channel
    const float alpha = 299792.458f - K1 * (f_lo - 2.0f * df) - vshift;
    const float inv_beta = __builtin_amdgcn_rcpf(beta);

    const float rlb = __builtin_amdgcn_rcpf(lb);
    const float sgs = 1.20112240878645f * rlb;      // sqrt(log2 e)/lb
    const float bp  = beta * sgs;                   // channel pitch, d' units
    const float tbp = 2.0f * bp;
    const float nbpsq = -bp * bp;

    // wave-uniform lattice constants c_j = 2^(-bp^2 j^2), built iteratively:
    // c_{j+1} = c_j * q1^(2j+1), with q1 = 2^(-bp^2), q2 = q1^2.
    float cj[WIN];
    {
        const float q2 = __builtin_amdgcn_exp2f(2.0f * nbpsq);
        float rq = __builtin_amdgcn_exp2f(nbpsq);
        cj[0] = 1.0f;
        #pragma unroll
        for (int j = 1; j < WIN; ++j) { cj[j] = cj[j - 1] * rq; rq *= q2; }
    }

    const float step  = 2000.0f / 127.0f;
    const float invrt = __builtin_amdgcn_rcpf(rturn);
    const float cA_r  = -LOG2E * __builtin_amdgcn_rcpf(rd);
    const float cA_z  = -LOG2E * __builtin_amdgcn_rcpf(hz);

    // ---- geometry: this lane's pixel, 8 z-points ----
    const float x = -1000.0f + (float)(2 * xo + (p >> 1)) * step;
    const float y = -1000.0f + (float)(2 * yo + (p & 1)) * step;
    const float rx   = cr * x - sr * y;
    const float u0   = sr * x + cr * y;
    const float crx  = -si * vmx * 0.636619772367581f * rx;  // v = crx*atan(t)/rad
    const float rx2e = fmaf(rx, rx, 1e-12f);
    const float zb0  = -1000.0f + (float)(zb * 8) * step;

    float v[8], A[8];
    #pragma unroll
    for (int k = 0; k < 8; ++k) {
        const float z  = zb0 + (float)k * step;
        const float ry = ci * u0 - si * z;
        const float rz = si * u0 + ci * z;
        const float r2 = fmaf(ry, ry, rx2e);
        const float ir = __builtin_amdgcn_rsqf(r2);
        const float rad = r2 * ir;
        // cheap atan: tm = min(t, 1/t); 5-coef poly (err ~1e-5 rad); reflect
        const float tg = rad * invrt;
        const float tm = fminf(tg, __builtin_amdgcn_rcpf(tg));
        const float x2 = tm * tm;
        float pl = fmaf(x2, 0.0208351f, -0.0851330f);
        pl = fmaf(x2, pl, 0.1801410f);
        pl = fmaf(x2, pl, -0.3302995f);
        pl = fmaf(x2, pl, 0.9998660f);
        pl *= tm;
        const float at = (tg > 1.0f) ? (1.57079632679f - pl) : pl;
        v[k] = crx * at * ir;                               // v_los
        A[k] = fmaf(rad, cA_r, fabsf(rz) * cA_z);           // log2 intensity
    }

    // ---- per-lane band base (floor-centering, round-7 proven config) ----
    float vlo = v[0], vhi = v[0];
    #pragma unroll
    for (int k = 1; k < 8; ++k) { vlo = fminf(vlo, v[k]); vhi = fmaxf(vhi, v[k]); }
    const float mid = 0.5f * (vlo + vhi);
    int basei = (int)floorf((alpha - mid) * inv_beta) - 5;
    basei = min(max(basei, 0), 64 - WIN);
    const float sWb  = sgs * fmaf(-beta, (float)basei, alpha);
    const float msgs = -sgs;

    // ---- 8z x 12ch KDE, factorized: term_j = E * rho^j * c_j  (2 exp2/z) ----
    float acc[WIN];
    #pragma unroll
    for (int j = 0; j < WIN; ++j) acc[j] = 0.0f;

    #pragma unroll
    for (int k = 0; k < 8; ++k) {
        const float Wk  = fmaf(msgs, v[k], sWb);                       // sgs*(Wb-v)
        const float E   = __builtin_amdgcn_exp2f(fmaf(-Wk, Wk, A[k])); // 2^(A-W^2)
        const float rho = __builtin_amdgcn_exp2f(tbp * Wk);            // 2^(2bp*W)
        const float rho2 = rho * rho;
        const float rho4 = rho2 * rho2;
        float tj[WIN];
        tj[0] = E;
        tj[1] = E * rho;
        tj[2] = E * rho2;
        tj[3] = tj[1] * rho2;
        #pragma unroll
        for (int j = 4; j < WIN; ++j) tj[j] = tj[j - 4] * rho4;
        #pragma unroll
        for (int j = 0; j < WIN; ++j) acc[j] = fmaf(tj[j], cj[j], acc[j]);
    }

    // ---- publish prefix sums: P[0]=0, P[j+1]=P[j]+acc[j]; and base ----
    const int rowb = lane * PSTRIDE;
    float P = 0.0f;
    s_P[rowb] = 0.0f;
    #pragma unroll
    for (int j = 0; j < WIN; ++j) { P += acc[j]; s_P[rowb + j + 1] = P; }
    s_base[lane] = basei;
    __syncthreads();

    // ---- gather: 4 lanes per coarse channel, 16 rows each, via P[hi]-P[lo] ----
    const int t16 = lane & 15;           // coarse channel
    const int g   = lane >> 4;           // row group
    const int c4  = t16 * 4;             // first fine channel of coarse t16
    const int gb  = g * 16;              // first row of this group
    float s = 0.0f;
    #pragma unroll
    for (int i = 0; i < 16; ++i) {
        const int b = s_base[gb + i];    // group-uniform -> broadcast, imm offset
        int lo = c4 - b;
        int hi = lo + 4;
        lo = min(max(lo, 0), WIN);
        hi = min(max(hi, 0), WIN);
        s += s_P[(gb + i) * PSTRIDE + hi] - s_P[(gb + i) * PSTRIDE + lo];
    }
    s += __shfl_xor(s, 16);
    s += __shfl_xor(s, 32);

    if (lane < 16) {
        // 1/16 pool * i0 / sqrt(2*pi*lb^2)
        const float scale = i0 * 0.0625f * 0.3989422804014327f * rlb;
        out[t16 * (IMG_OUT * IMG_OUT) + xo * IMG_OUT + yo] = s * scale;
    }
}

extern "C" void kernel_launch(void* const* d_in, const int* in_sizes, int n_in,
                              void* d_out, int out_size, void* d_ws, size_t ws_size,
                              hipStream_t stream) {
    (void)in_sizes; (void)n_in; (void)d_ws; (void)ws_size; (void)out_size;
    const float* freqs  = (const float*)d_in[0];
    const float* incl   = (const float*)d_in[1];
    const float* rot    = (const float*)d_in[2];
    const float* lb     = (const float*)d_in[3];
    const float* vshift = (const float*)d_in[4];
    const float* vmax   = (const float*)d_in[5];
    const float* rturn  = (const float*)d_in[6];
    const float* i0     = (const float*)d_in[7];
    const float* rd     = (const float*)d_in[8];
    const float* hz     = (const float*)d_in[9];
    float* out = (float*)d_out;

    dim3 grid(IMG_OUT, IMG_OUT);
    dim3 block(64);
    hipLaunchKernelGGL(cube_sim_kernel, grid, block, 0, stream,
                       freqs, incl, rot, lb, vshift, vmax, rturn, i0, rd, hz, out);
}

// Round 11
// 10.999 us; speedup vs baseline: 1.3081x; 1.0492x over previous
//
#include <hip/hip_runtime.h>
#include <math.h>

#define IMG_OUT 64
#define WIN 12          // per-lane band window (fine channels) — proven R7/R10
#define DSTRIDE 17      // D-row: [guard, D(-3..11), guard]; odd stride -> 2-way alias = free

__global__ __launch_bounds__(64, 4) void cube_sim_kernel(
    const float* __restrict__ freqs,
    const float* __restrict__ p_incl,
    const float* __restrict__ p_rot,
    const float* __restrict__ p_lb,
    const float* __restrict__ p_vshift,
    const float* __restrict__ p_vmax,
    const float* __restrict__ p_rturn,
    const float* __restrict__ p_i0,
    const float* __restrict__ p_rd,
    const float* __restrict__ p_hz,
    float* __restrict__ out)
{
    const int lane = threadIdx.x;      // 0..63
    const int xo = blockIdx.x, yo = blockIdx.y;
    const int p  = lane >> 4;          // internal pixel 0..3
    const int zb = lane & 15;          // z-block (8 z each)

    __shared__ float s_D[64 * DSTRIDE];   // per-row guarded window sums
    __shared__ int   s_base[64];          // per-row band base

    // ---- scalars (uniform -> s_load) ----
    const float incl   = p_incl[0];
    const float rot    = p_rot[0];
    const float lb     = p_lb[0];
    const float vshift = p_vshift[0];
    const float vmx    = p_vmax[0];
    const float rturn  = p_rturn[0];
    const float i0     = p_i0[0];
    const float rd     = p_rd[0];
    const float hz     = p_hz[0];

    const float LOG2E = 1.4426950408889634f;
    const float ci = __cosf(incl), si = __sinf(incl);
    const float cr = __cosf(rot),  sr = __sinf(rot);

    const float K1   = 299792.458f / 230.538f;      // C_KMS / F_REST
    const float f_lo = freqs[0];
    const float df   = (freqs[15] - f_lo) * (1.0f / 63.0f);
    const float beta = K1 * df;                     // km/s per fine channel
    const float alpha = 299792.458f - K1 * (f_lo - 2.0f * df) - vshift;
    const float inv_beta = __builtin_amdgcn_rcpf(beta);

    const float rlb = __builtin_amdgcn_rcpf(lb);
    const float sgs = 1.20112240878645f * rlb;      // sqrt(log2 e)/lb
    const float bp  = beta * sgs;                   // channel pitch, d' units
    const float tbp = 2.0f * bp;
    const float nbpsq = -bp * bp;

    // wave-uniform lattice constants c_j = 2^(-bp^2 j^2), built iteratively
    float cj[WIN];
    {
        const float q2 = __builtin_amdgcn_exp2f(2.0f * nbpsq);
        float rq = __builtin_amdgcn_exp2f(nbpsq);
        cj[0] = 1.0f;
        #pragma unroll
        for (int j = 1; j < WIN; ++j) { cj[j] = cj[j - 1] * rq; rq *= q2; }
    }

    const float step  = 2000.0f / 127.0f;
    const float invrt = __builtin_amdgcn_rcpf(rturn);
    const float cA_r  = -LOG2E * __builtin_amdgcn_rcpf(rd);
    const float cA_z  = -LOG2E * __builtin_amdgcn_rcpf(hz);

    // ---- geometry: this lane's pixel, 8 z-points (incremental ry/rz) ----
    const float x = -1000.0f + (float)(2 * xo + (p >> 1)) * step;
    const float y = -1000.0f + (float)(2 * yo + (p & 1)) * step;
    const float rx   = cr * x - sr * y;
    const float u0   = sr * x + cr * y;
    const float crx  = -si * vmx * 0.636619772367581f * rx;  // v = crx*atan(t)/rad
    const float rx2e = fmaf(rx, rx, 1e-12f);
    const float zb0  = -1000.0f + (float)(zb * 8) * step;

    float ry = ci * u0 - si * zb0;
    float rz = si * u0 + ci * zb0;
    const float dry = -si * step, drz = ci * step;

    float v[8], A[8];
    #pragma unroll
    for (int k = 0; k < 8; ++k) {
        const float r2 = fmaf(ry, ry, rx2e);
        const float ir = __builtin_amdgcn_rsqf(r2);
        const float rad = r2 * ir;
        // cheap atan: tm = min(t, 1/t); 5-coef poly (err ~1e-5 rad); reflect
        const float tg = rad * invrt;
        const float tm = fminf(tg, __builtin_amdgcn_rcpf(tg));
        const float x2 = tm * tm;
        float pl = fmaf(x2, 0.0208351f, -0.0851330f);
        pl = fmaf(x2, pl, 0.1801410f);
        pl = fmaf(x2, pl, -0.3302995f);
        pl = fmaf(x2, pl, 0.9998660f);
        pl *= tm;
        const float at = (tg > 1.0f) ? (1.57079632679f - pl) : pl;
        v[k] = crx * at * ir;                               // v_los
        A[k] = fmaf(rad, cA_r, fabsf(rz) * cA_z);           // log2 intensity
        ry += dry; rz += drz;
    }

    // ---- per-lane band base (floor-centering, proven config) ----
    float vlo = v[0], vhi = v[0];
    #pragma unroll
    for (int k = 1; k < 8; ++k) { vlo = fminf(vlo, v[k]); vhi = fmaxf(vhi, v[k]); }
    const float mid = 0.5f * (vlo + vhi);
    int basei = (int)floorf((alpha - mid) * inv_beta) - 5;
    basei = min(max(basei, 0), 64 - WIN);
    const float sWb  = sgs * fmaf(-beta, (float)basei, alpha);
    const float msgs = -sgs;

    // ---- 8z x 12ch KDE, factorized: term_j = E * rho^j * c_j  (2 exp2/z) ----
    float acc[WIN];
    #pragma unroll
    for (int j = 0; j < WIN; ++j) acc[j] = 0.0f;

    #pragma unroll
    for (int k = 0; k < 8; ++k) {
        const float Wk  = fmaf(msgs, v[k], sWb);                       // sgs*(Wb-v)
        const float E   = __builtin_amdgcn_exp2f(fmaf(-Wk, Wk, A[k])); // 2^(A-W^2)
        const float rho = __builtin_amdgcn_exp2f(tbp * Wk);            // 2^(2bp*W)
        const float rho2 = rho * rho;
        const float rho4 = rho2 * rho2;
        float tj[WIN];
        tj[0] = E;
        tj[1] = E * rho;
        tj[2] = E * rho2;
        tj[3] = tj[1] * rho2;
        #pragma unroll
        for (int j = 4; j < WIN; ++j) tj[j] = tj[j - 4] * rho4;
        #pragma unroll
        for (int j = 0; j < WIN; ++j) acc[j] = fmaf(tj[j], cj[j], acc[j]);
    }

    // ---- publish guarded window sums D[m] = P[min(m+4,12)] - P[max(m,0)] ----
    float Pr[WIN + 1];
    Pr[0] = 0.0f;
    #pragma unroll
    for (int j = 0; j < WIN; ++j) Pr[j + 1] = Pr[j] + acc[j];

    const int rowb = lane * DSTRIDE;
    s_D[rowb + 0]  = 0.0f;               // guard: lo <= -4
    #pragma unroll
    for (int m = -3; m <= 11; ++m) {     // all indices compile-time after unroll
        const int u = (m + 4 < WIN) ? (m + 4) : WIN;
        const int l = (m > 0) ? m : 0;
        s_D[rowb + 4 + m] = Pr[u] - Pr[l];
    }
    s_D[rowb + 16] = 0.0f;               // guard: lo >= 12
    s_base[lane] = basei;
    __syncthreads();

    // ---- gather: 4 lanes per coarse channel, 16 rows each, 1 read/row ----
    const int t16 = lane & 15;           // coarse channel
    const int g   = lane >> 4;           // row group
    const int c4  = t16 * 4;             // first fine channel of coarse t16
    const int gb  = g * 16;              // first row of this group
    float s = 0.0f;
    #pragma unroll
    for (int i = 0; i < 16; ++i) {
        const int b = s_base[gb + i];    // group-uniform -> broadcast
        const int m = min(max(c4 - b, -4), 12);   // med3 clamp into guarded row
        s += s_D[(gb + i) * DSTRIDE + 4 + m];
    }
    s += __shfl_xor(s, 16);
    s += __shfl_xor(s, 32);

    if (lane < 16) {
        // 1/16 pool * i0 / sqrt(2*pi*lb^2)
        const float scale = i0 * 0.0625f * 0.3989422804014327f * rlb;
        out[t16 * (IMG_OUT * IMG_OUT) + xo * IMG_OUT + yo] = s * scale;
    }
}

extern "C" void kernel_launch(void* const* d_in, const int* in_sizes, int n_in,
                              void* d_out, int out_size, void* d_ws, size_t ws_size,
                              hipStream_t stream) {
    (void)in_sizes; (void)n_in; (void)d_ws; (void)ws_size; (void)out_size;
    const float* freqs  = (const float*)d_in[0];
    const float* incl   = (const float*)d_in[1];
    const float* rot    = (const float*)d_in[2];
    const float* lb     = (const float*)d_in[3];
    const float* vshift = (const float*)d_in[4];
    const float* vmax   = (const float*)d_in[5];
    const float* rturn  = (const float*)d_in[6];
    const float* i0     = (const float*)d_in[7];
    const float* rd     = (const float*)d_in[8];
    const float* hz     = (const float*)d_in[9];
    float* out = (float*)d_out;

    dim3 grid(IMG_OUT, IMG_OUT);
    dim3 block(64);
    hipLaunchKernelGGL(cube_sim_kernel, grid, block, 0, stream,
                       freqs, incl, rot, lb, vshift, vmax, rturn, i0, rd, hz, out);
}